// Round 1
// baseline (3607.161 us; speedup 1.0000x reference)
//
#include <hip/hip_runtime.h>
#include <math.h>

#define N_NODES 50000
#define N_EDGES 800000
#define HDIM 128
#define K1 273        // 2H + EDGE_DIM + 1
#define ME 128        // edges per block
#define NB 64         // nodes per block
#define SAS 36        // sA row stride (floats), padded for bank behavior
#define SWS 36        // sW row stride (floats)

__device__ __forceinline__ float silu_f(float v) {
    return v / (1.0f + __expf(-v));
}

// Stage a 32-wide K-chunk of W (K x 128, k-major in global) transposed into
// LDS as sW[c*SWS + kr], zero-padded for k >= kmax.
__device__ __forceinline__ void stage_w(const float* __restrict__ W, int k0, int kmax,
                                        int tid, float* __restrict__ sW) {
#pragma unroll
    for (int it = 0; it < 16; ++it) {
        int f = tid + 256 * it;       // 0..4095 covers 128c x 32k
        int c = f & 127;
        int kk = f >> 7;              // 0..31
        int kg = k0 + kk;
        sW[c * SWS + kk] = (kg < kmax) ? W[kg * HDIM + c] : 0.0f;
    }
}

// One 32-wide K-chunk of the register-tiled GEMM.
// Thread owns rows {rg + 16*i, i<R} and cols {colg + 16*j, j<8}.
template <int R>
__device__ __forceinline__ void gemm_chunk(const float* __restrict__ sA,
                                           const float* __restrict__ sW,
                                           int rg, int colg, float (&acc)[R][8]) {
    for (int k4 = 0; k4 < 8; ++k4) {
        float4 a[R], w[8];
#pragma unroll
        for (int i = 0; i < R; ++i)
            a[i] = *(const float4*)&sA[(rg + 16 * i) * SAS + k4 * 4];
#pragma unroll
        for (int j = 0; j < 8; ++j)
            w[j] = *(const float4*)&sW[(colg + 16 * j) * SWS + k4 * 4];
#pragma unroll
        for (int i = 0; i < R; ++i)
#pragma unroll
            for (int j = 0; j < 8; ++j) {
                acc[i][j] = fmaf(a[i].x, w[j].x, acc[i][j]);
                acc[i][j] = fmaf(a[i].y, w[j].y, acc[i][j]);
                acc[i][j] = fmaf(a[i].z, w[j].z, acc[i][j]);
                acc[i][j] = fmaf(a[i].w, w[j].w, acc[i][j]);
            }
    }
}

__global__ __launch_bounds__(256, 2)
void egnn_edge_kernel(const float* __restrict__ h, const float* __restrict__ x,
                      const int* __restrict__ ei, const float* __restrict__ ea,
                      const float* __restrict__ We1, const float* __restrict__ be1,
                      const float* __restrict__ We2, const float* __restrict__ be2,
                      const float* __restrict__ Wx1, const float* __restrict__ bx1,
                      const float* __restrict__ Wx2, const float* __restrict__ bx2,
                      float* __restrict__ agg, float* __restrict__ dxb) {
    __shared__ __align__(16) float sA[ME * SAS];
    __shared__ __align__(16) float sW[HDIM * SWS];
    __shared__ int s_src[ME], s_dst[ME];
    __shared__ float s_dist[ME];
    __shared__ float s_dir[ME * 3];

    const int tid = threadIdx.x;
    const int colg = tid & 15;
    const int eg = tid >> 4;
    const int e0 = blockIdx.x * ME;

    // Per-edge preamble: indices, dist, unit direction.
    if (tid < ME) {
        int e = e0 + tid;
        int s = ei[e];
        int d = ei[N_EDGES + e];
        s_src[tid] = s;
        s_dst[tid] = d;
        float ddx = x[d * 3 + 0] - x[s * 3 + 0];
        float ddy = x[d * 3 + 1] - x[s * 3 + 1];
        float ddz = x[d * 3 + 2] - x[s * 3 + 2];
        float dot = ddx * ddx + ddy * ddy + ddz * ddz;
        s_dist[tid] = sqrtf(dot + 1e-9f);              // dist: eps inside sqrt
        float inv = 1.0f / (sqrtf(dot) + 1e-9f);       // dir_norm: eps outside
        s_dir[tid * 3 + 0] = ddx * inv;
        s_dir[tid * 3 + 1] = ddy * inv;
        s_dir[tid * 3 + 2] = ddz * inv;
    }
    __syncthreads();

    // ---- phi_e layer 1: m_in(273) @ We1 -> t1 (silu later)
    float acc1[8][8];
#pragma unroll
    for (int i = 0; i < 8; ++i)
#pragma unroll
        for (int j = 0; j < 8; ++j) acc1[i][j] = 0.0f;

    for (int kc = 0; kc < 9; ++kc) {
        const int k0 = kc * 32;
        // Stage A chunk: [h_src | h_dst | edge_attr | dist | 0-pad]
#pragma unroll
        for (int q = 0; q < 4; ++q) {
            int f = tid + 256 * q;       // 1024 float4 slots = 128e x 8 quads
            int e = f >> 3;
            int k4 = f & 7;
            int kk = k0 + k4 * 4;
            float4 v = make_float4(0.0f, 0.0f, 0.0f, 0.0f);
            if (kk < 128)       v = *(const float4*)&h[s_src[e] * HDIM + kk];
            else if (kk < 256)  v = *(const float4*)&h[s_dst[e] * HDIM + (kk - 128)];
            else if (kk < 272)  v = *(const float4*)&ea[(e0 + e) * 16 + (kk - 256)];
            else if (kk == 272) v = make_float4(s_dist[e], 0.0f, 0.0f, 0.0f);
            *(float4*)&sA[e * SAS + k4 * 4] = v;
        }
        stage_w(We1, k0, K1, tid, sW);
        __syncthreads();
        gemm_chunk<8>(sA, sW, eg, colg, acc1);
        __syncthreads();
    }
#pragma unroll
    for (int j = 0; j < 8; ++j) {
        float b = be1[colg + 16 * j];
#pragma unroll
        for (int i = 0; i < 8; ++i) acc1[i][j] = silu_f(acc1[i][j] + b);
    }

    // ---- phi_e layer 2: t1 @ We2 + be2 -> m
    float acc2[8][8];
#pragma unroll
    for (int i = 0; i < 8; ++i)
#pragma unroll
        for (int j = 0; j < 8; ++j) acc2[i][j] = 0.0f;

    for (int kc = 0; kc < 4; ++kc) {
        const int k0 = kc * 32;
        const int jb = k0 >> 4;
#pragma unroll
        for (int i = 0; i < 8; ++i) {
            sA[(eg + 16 * i) * SAS + colg]      = acc1[i][jb];
            sA[(eg + 16 * i) * SAS + colg + 16] = acc1[i][jb + 1];
        }
        stage_w(We2, k0, HDIM, tid, sW);
        __syncthreads();
        gemm_chunk<8>(sA, sW, eg, colg, acc2);
        __syncthreads();
    }
#pragma unroll
    for (int j = 0; j < 8; ++j) {
        float b = be2[colg + 16 * j];
#pragma unroll
        for (int i = 0; i < 8; ++i) acc2[i][j] += b;
    }

    // Scatter m into agg[dst]
#pragma unroll
    for (int i = 0; i < 8; ++i) {
        int d = s_dst[eg + 16 * i];
#pragma unroll
        for (int j = 0; j < 8; ++j)
            atomicAdd(&agg[d * HDIM + colg + 16 * j], acc2[i][j]);
    }

    // ---- phi_x layer 1: u = silu(m @ Wx1 + bx1)  (A chunks staged from m regs)
    float acc3[8][8];
#pragma unroll
    for (int i = 0; i < 8; ++i)
#pragma unroll
        for (int j = 0; j < 8; ++j) acc3[i][j] = 0.0f;

    for (int kc = 0; kc < 4; ++kc) {
        const int k0 = kc * 32;
        const int jb = k0 >> 4;
#pragma unroll
        for (int i = 0; i < 8; ++i) {
            sA[(eg + 16 * i) * SAS + colg]      = acc2[i][jb];
            sA[(eg + 16 * i) * SAS + colg + 16] = acc2[i][jb + 1];
        }
        stage_w(Wx1, k0, HDIM, tid, sW);
        __syncthreads();
        gemm_chunk<8>(sA, sW, eg, colg, acc3);
        __syncthreads();
    }

    // gate = u @ Wx2 + bx2 ; dx scatter
    float gp[8];
#pragma unroll
    for (int i = 0; i < 8; ++i) gp[i] = 0.0f;
#pragma unroll
    for (int j = 0; j < 8; ++j) {
        int c = colg + 16 * j;
        float wj = Wx2[c];
        float bj = bx1[c];
#pragma unroll
        for (int i = 0; i < 8; ++i) gp[i] += silu_f(acc3[i][j] + bj) * wj;
    }
#pragma unroll
    for (int m = 1; m < 16; m <<= 1)
#pragma unroll
        for (int i = 0; i < 8; ++i) gp[i] += __shfl_xor(gp[i], m);

    if (colg == 0) {
        float b2 = bx2[0];
#pragma unroll
        for (int i = 0; i < 8; ++i) {
            int e = eg + 16 * i;
            int d = s_dst[e];
            float g = gp[i] + b2;
            atomicAdd(&dxb[d * 3 + 0], s_dir[e * 3 + 0] * g);
            atomicAdd(&dxb[d * 3 + 1], s_dir[e * 3 + 1] * g);
            atomicAdd(&dxb[d * 3 + 2], s_dir[e * 3 + 2] * g);
        }
    }
}

__global__ __launch_bounds__(256, 2)
void egnn_node_kernel(const float* __restrict__ h, const float* __restrict__ x,
                      const float* __restrict__ agg, const float* __restrict__ dxb,
                      const float* __restrict__ Wh1, const float* __restrict__ bh1,
                      const float* __restrict__ Wh2, const float* __restrict__ bh2,
                      const float* __restrict__ ln_g, const float* __restrict__ ln_b,
                      float* __restrict__ hout, float* __restrict__ xout) {
    __shared__ __align__(16) float sA[NB * SAS];
    __shared__ __align__(16) float sW[HDIM * SWS];

    const int tid = threadIdx.x;
    const int colg = tid & 15;
    const int ng = tid >> 4;
    const int n0 = blockIdx.x * NB;

    // ---- phi_h layer 1: [h | agg](256) @ Wh1
    float acc1[4][8];
#pragma unroll
    for (int i = 0; i < 4; ++i)
#pragma unroll
        for (int j = 0; j < 8; ++j) acc1[i][j] = 0.0f;

    for (int kc = 0; kc < 8; ++kc) {
        const int k0 = kc * 32;
#pragma unroll
        for (int q = 0; q < 2; ++q) {
            int f = tid + 256 * q;       // 512 float4 slots = 64n x 8 quads
            int e = f >> 3;
            int k4 = f & 7;
            int kk = k0 + k4 * 4;
            int n = n0 + e;
            float4 v = make_float4(0.0f, 0.0f, 0.0f, 0.0f);
            if (n < N_NODES)
                v = (kk < 128) ? *(const float4*)&h[n * HDIM + kk]
                               : *(const float4*)&agg[n * HDIM + (kk - 128)];
            *(float4*)&sA[e * SAS + k4 * 4] = v;
        }
        stage_w(Wh1, k0, 256, tid, sW);
        __syncthreads();
        gemm_chunk<4>(sA, sW, ng, colg, acc1);
        __syncthreads();
    }
#pragma unroll
    for (int j = 0; j < 8; ++j) {
        float b = bh1[colg + 16 * j];
#pragma unroll
        for (int i = 0; i < 4; ++i) acc1[i][j] = silu_f(acc1[i][j] + b);
    }

    // ---- phi_h layer 2
    float acc2[4][8];
#pragma unroll
    for (int i = 0; i < 4; ++i)
#pragma unroll
        for (int j = 0; j < 8; ++j) acc2[i][j] = 0.0f;

    for (int kc = 0; kc < 4; ++kc) {
        const int k0 = kc * 32;
        const int jb = k0 >> 4;
#pragma unroll
        for (int i = 0; i < 4; ++i) {
            sA[(ng + 16 * i) * SAS + colg]      = acc1[i][jb];
            sA[(ng + 16 * i) * SAS + colg + 16] = acc1[i][jb + 1];
        }
        stage_w(Wh2, k0, HDIM, tid, sW);
        __syncthreads();
        gemm_chunk<4>(sA, sW, ng, colg, acc2);
        __syncthreads();
    }

    // ---- residual + LayerNorm
#pragma unroll
    for (int i = 0; i < 4; ++i) {
        int n = n0 + ng + 16 * i;
        if (n < N_NODES) {               // uniform across each 16-lane group
            float v[8];
            float S1 = 0.0f, S2 = 0.0f;
#pragma unroll
            for (int j = 0; j < 8; ++j) {
                int c = colg + 16 * j;
                v[j] = h[n * HDIM + c] + acc2[i][j] + bh2[c];
                S1 += v[j];
                S2 += v[j] * v[j];
            }
#pragma unroll
            for (int m = 1; m < 16; m <<= 1) {
                S1 += __shfl_xor(S1, m);
                S2 += __shfl_xor(S2, m);
            }
            float mu = S1 * (1.0f / 128.0f);
            float var = S2 * (1.0f / 128.0f) - mu * mu;
            float rs = rsqrtf(var + 1e-5f);
#pragma unroll
            for (int j = 0; j < 8; ++j) {
                int c = colg + 16 * j;
                hout[n * HDIM + c] = (v[j] - mu) * rs * ln_g[c] + ln_b[c];
            }
        }
    }

    // ---- x_out = x + dx
    if (tid < NB * 3) {
        int e = tid / 3;
        int d2 = tid - e * 3;
        int n = n0 + e;
        if (n < N_NODES) xout[n * 3 + d2] = x[n * 3 + d2] + dxb[n * 3 + d2];
    }
}

extern "C" void kernel_launch(void* const* d_in, const int* in_sizes, int n_in,
                              void* d_out, int out_size, void* d_ws, size_t ws_size,
                              hipStream_t stream) {
    (void)in_sizes; (void)n_in; (void)out_size;

    const float* h   = (const float*)d_in[0];
    const float* x   = (const float*)d_in[1];
    const int*   ei  = (const int*)d_in[2];
    const float* ea  = (const float*)d_in[3];
    const float* We1 = (const float*)d_in[4];
    const float* be1 = (const float*)d_in[5];
    const float* We2 = (const float*)d_in[6];
    const float* be2 = (const float*)d_in[7];
    const float* Wh1 = (const float*)d_in[8];
    const float* bh1 = (const float*)d_in[9];
    const float* Wh2 = (const float*)d_in[10];
    const float* bh2 = (const float*)d_in[11];
    const float* Wx1 = (const float*)d_in[12];
    const float* bx1 = (const float*)d_in[13];
    const float* Wx2 = (const float*)d_in[14];
    const float* bx2 = (const float*)d_in[15];
    const float* lng = (const float*)d_in[16];
    const float* lnb = (const float*)d_in[17];

    float* hout = (float*)d_out;
    float* xout = hout + (size_t)N_NODES * HDIM;

    const size_t need = ((size_t)N_NODES * HDIM + (size_t)N_NODES * 3) * sizeof(float);
    // Prefer workspace; fall back to aliasing d_out (safe: each node-kernel
    // block reads its agg/dx rows before writing h_out/x_out to them).
    float* agg = (ws_size >= need) ? (float*)d_ws : (float*)d_out;
    float* dxb = agg + (size_t)N_NODES * HDIM;

    hipMemsetAsync(agg, 0, need, stream);
    egnn_edge_kernel<<<N_EDGES / ME, 256, 0, stream>>>(
        h, x, ei, ea, We1, be1, We2, be2, Wx1, bx1, Wx2, bx2, agg, dxb);
    egnn_node_kernel<<<(N_NODES + NB - 1) / NB, 256, 0, stream>>>(
        h, x, agg, dxb, Wh1, bh1, Wh2, bh2, lng, lnb, hout, xout);
}

// Round 2
// 710.568 us; speedup vs baseline: 5.0764x; 5.0764x over previous
//
#include <hip/hip_runtime.h>
#include <math.h>

#define N_NODES 50000
#define N_EDGES 800000
#define HDIM 128

typedef __attribute__((ext_vector_type(8))) short bf16x8;
typedef __attribute__((ext_vector_type(4))) float floatx4;

__device__ __forceinline__ unsigned f2bf_u(float f) {
    union { float f; unsigned u; } x; x.f = f;
    return (x.u + 0x7FFFu + ((x.u >> 16) & 1u)) >> 16;
}
__device__ __forceinline__ short f2bf(float f) { return (short)f2bf_u(f); }
__device__ __forceinline__ float silu_f(float v) { return v / (1.0f + __expf(-v)); }

// Swizzled LDS index for the 128x128 bf16 activation buffer.
// 16B blocks along k are XOR-swizzled by (row>>1)&7 so that both the
// C-layout b16 writes (quads land in disjoint bank octets) and the
// A-fragment b128 reads (uniform 8 accesses/bank) are conflict-free.
__device__ __forceinline__ int sT_idx(int row, int c) {
    int kb = (c >> 3) ^ ((row >> 1) & 7);
    return row * 128 + kb * 8 + (c & 7);
}

#define SA_STRIDE 40  // bf16 per staged A row (80 B: conflict-free for frag reads)

// ---- weight packing: W (K x 128 fp32, k-major) -> bf16 MFMA B-frag order ----
// dst[((kc*8+ct)*64 + lane)*8 + j] = bf16(W[(kc*32 + (lane>>4)*8 + j)*128 + ct*16 + (lane&15)])
__global__ void pack_w_kernel(const float* __restrict__ W, short* __restrict__ dst,
                              int K, int total) {
    int t = blockIdx.x * 256 + threadIdx.x;
    if (t >= total) return;
    int lane = t & 63;
    int ctk = t >> 6;
    int ct = ctk & 7, kc = ctk >> 3;
    int c = ct * 16 + (lane & 15);
    int kb = kc * 32 + (lane >> 4) * 8;
    bf16x8 v;
#pragma unroll
    for (int j = 0; j < 8; ++j) {
        int k = kb + j;
        v[j] = (k < K) ? f2bf(W[(size_t)k * HDIM + c]) : (short)0;
    }
    *(bf16x8*)&dst[(size_t)t * 8] = v;
}

__global__ __launch_bounds__(256, 3)
void egnn_edge_mfma(const float* __restrict__ h, const float* __restrict__ x,
                    const int* __restrict__ ei, const float* __restrict__ ea,
                    const short* __restrict__ pWe1, const short* __restrict__ pWe2,
                    const short* __restrict__ pWx1,
                    const float* __restrict__ be1, const float* __restrict__ be2,
                    const float* __restrict__ bx1, const float* __restrict__ Wx2,
                    const float* __restrict__ bx2,
                    float* __restrict__ agg, float* __restrict__ dxb) {
    __shared__ __align__(16) short sA[128 * SA_STRIDE];
    __shared__ __align__(16) short sT[128 * 128];
    __shared__ int s_src[128], s_dst[128];
    __shared__ float s_dist[128], s_dir[128 * 3], sGate[128];

    const int tid = threadIdx.x;
    const int lane = tid & 63;
    const int w = tid >> 6;
    const int lc = lane & 15;
    const int quad = lane >> 4;
    const int e0 = blockIdx.x * 128;
    const int srow = tid >> 1;
    const int hf = tid & 1;

    if (tid < 128) {
        int e = e0 + tid;
        int s = ei[e], d = ei[N_EDGES + e];
        s_src[tid] = s; s_dst[tid] = d;
        float ddx = x[d * 3 + 0] - x[s * 3 + 0];
        float ddy = x[d * 3 + 1] - x[s * 3 + 1];
        float ddz = x[d * 3 + 2] - x[s * 3 + 2];
        float dot = ddx * ddx + ddy * ddy + ddz * ddz;
        s_dist[tid] = sqrtf(dot + 1e-9f);
        float inv = 1.0f / (sqrtf(dot) + 1e-9f);
        s_dir[tid * 3 + 0] = ddx * inv;
        s_dir[tid * 3 + 1] = ddy * inv;
        s_dir[tid * 3 + 2] = ddz * inv;
        sGate[tid] = 0.0f;
    }
    __syncthreads();

    const int ct0 = 2 * w, ct1 = 2 * w + 1;
    const int c0 = ct0 * 16 + lc, c1 = c0 + 16;

    floatx4 acc[8][2];
#pragma unroll
    for (int rt = 0; rt < 8; ++rt)
#pragma unroll
        for (int ct = 0; ct < 2; ++ct)
#pragma unroll
            for (int r = 0; r < 4; ++r) acc[rt][ct][r] = 0.0f;

    // ---- phi_e layer 1: K = 288 (273 + zero pad) ----
    for (int kc = 0; kc < 9; ++kc) {
        {
            float tmp[16];
            if (kc < 8) {
                int base = (kc < 4) ? s_src[srow] : s_dst[srow];
                int koff = (kc & 3) * 32 + hf * 16;
                const float4* p = (const float4*)&h[(size_t)base * HDIM + koff];
#pragma unroll
                for (int q = 0; q < 4; ++q) {
                    float4 v = p[q];
                    tmp[4 * q + 0] = v.x; tmp[4 * q + 1] = v.y;
                    tmp[4 * q + 2] = v.z; tmp[4 * q + 3] = v.w;
                }
            } else if (hf == 0) {
                const float4* p = (const float4*)&ea[(size_t)(e0 + srow) * 16];
#pragma unroll
                for (int q = 0; q < 4; ++q) {
                    float4 v = p[q];
                    tmp[4 * q + 0] = v.x; tmp[4 * q + 1] = v.y;
                    tmp[4 * q + 2] = v.z; tmp[4 * q + 3] = v.w;
                }
            } else {
#pragma unroll
                for (int i = 0; i < 16; ++i) tmp[i] = 0.0f;
                tmp[0] = s_dist[srow];
            }
            unsigned wd[8];
#pragma unroll
            for (int i = 0; i < 8; ++i)
                wd[i] = f2bf_u(tmp[2 * i]) | (f2bf_u(tmp[2 * i + 1]) << 16);
            uint4* dst = (uint4*)&sA[srow * SA_STRIDE + hf * 16];
            dst[0] = make_uint4(wd[0], wd[1], wd[2], wd[3]);
            dst[1] = make_uint4(wd[4], wd[5], wd[6], wd[7]);
        }
        __syncthreads();
        bf16x8 b0 = *(const bf16x8*)&pWe1[((size_t)(kc * 8 + ct0) * 64 + lane) * 8];
        bf16x8 b1 = *(const bf16x8*)&pWe1[((size_t)(kc * 8 + ct1) * 64 + lane) * 8];
#pragma unroll
        for (int rt = 0; rt < 8; ++rt) {
            bf16x8 a = *(const bf16x8*)&sA[(rt * 16 + lc) * SA_STRIDE + quad * 8];
            acc[rt][0] = __builtin_amdgcn_mfma_f32_16x16x32_bf16(a, b0, acc[rt][0], 0, 0, 0);
            acc[rt][1] = __builtin_amdgcn_mfma_f32_16x16x32_bf16(a, b1, acc[rt][1], 0, 0, 0);
        }
        __syncthreads();
    }

    // epilogue 1: bias + silu -> sT (bf16, swizzled)
    {
        float bb0 = be1[c0], bb1 = be1[c1];
#pragma unroll
        for (int rt = 0; rt < 8; ++rt)
#pragma unroll
            for (int r = 0; r < 4; ++r) {
                int row = rt * 16 + quad * 4 + r;
                sT[sT_idx(row, c0)] = f2bf(silu_f(acc[rt][0][r] + bb0));
                sT[sT_idx(row, c1)] = f2bf(silu_f(acc[rt][1][r] + bb1));
            }
    }
    __syncthreads();

    // ---- phi_e layer 2: m = t1 @ We2 + be2 ----
#pragma unroll
    for (int rt = 0; rt < 8; ++rt)
#pragma unroll
        for (int ct = 0; ct < 2; ++ct)
#pragma unroll
            for (int r = 0; r < 4; ++r) acc[rt][ct][r] = 0.0f;

    for (int kc = 0; kc < 4; ++kc) {
        bf16x8 b0 = *(const bf16x8*)&pWe2[((size_t)(kc * 8 + ct0) * 64 + lane) * 8];
        bf16x8 b1 = *(const bf16x8*)&pWe2[((size_t)(kc * 8 + ct1) * 64 + lane) * 8];
#pragma unroll
        for (int rt = 0; rt < 8; ++rt) {
            int kb = (kc * 4 + quad) ^ ((lc >> 1) & 7);
            bf16x8 a = *(const bf16x8*)&sT[(rt * 16 + lc) * 128 + kb * 8];
            acc[rt][0] = __builtin_amdgcn_mfma_f32_16x16x32_bf16(a, b0, acc[rt][0], 0, 0, 0);
            acc[rt][1] = __builtin_amdgcn_mfma_f32_16x16x32_bf16(a, b1, acc[rt][1], 0, 0, 0);
        }
    }
    {
        float bb0 = be2[c0], bb1 = be2[c1];
#pragma unroll
        for (int rt = 0; rt < 8; ++rt)
#pragma unroll
            for (int r = 0; r < 4; ++r) {
                acc[rt][0][r] += bb0;
                acc[rt][1][r] += bb1;
            }
    }
    __syncthreads();   // all waves done reading t1 from sT

    // scatter m -> agg (fp32 atomics) and write m -> sT for phi_x
#pragma unroll
    for (int rt = 0; rt < 8; ++rt)
#pragma unroll
        for (int r = 0; r < 4; ++r) {
            int row = rt * 16 + quad * 4 + r;
            int d = s_dst[row];
            atomicAdd(&agg[(size_t)d * HDIM + c0], acc[rt][0][r]);
            atomicAdd(&agg[(size_t)d * HDIM + c1], acc[rt][1][r]);
            sT[sT_idx(row, c0)] = f2bf(acc[rt][0][r]);
            sT[sT_idx(row, c1)] = f2bf(acc[rt][1][r]);
        }
    __syncthreads();

    // ---- phi_x: u = silu(m @ Wx1 + bx1); gate = u . Wx2 + bx2 ----
#pragma unroll
    for (int rt = 0; rt < 8; ++rt)
#pragma unroll
        for (int ct = 0; ct < 2; ++ct)
#pragma unroll
            for (int r = 0; r < 4; ++r) acc[rt][ct][r] = 0.0f;

    for (int kc = 0; kc < 4; ++kc) {
        bf16x8 b0 = *(const bf16x8*)&pWx1[((size_t)(kc * 8 + ct0) * 64 + lane) * 8];
        bf16x8 b1 = *(const bf16x8*)&pWx1[((size_t)(kc * 8 + ct1) * 64 + lane) * 8];
#pragma unroll
        for (int rt = 0; rt < 8; ++rt) {
            int kb = (kc * 4 + quad) ^ ((lc >> 1) & 7);
            bf16x8 a = *(const bf16x8*)&sT[(rt * 16 + lc) * 128 + kb * 8];
            acc[rt][0] = __builtin_amdgcn_mfma_f32_16x16x32_bf16(a, b0, acc[rt][0], 0, 0, 0);
            acc[rt][1] = __builtin_amdgcn_mfma_f32_16x16x32_bf16(a, b1, acc[rt][1], 0, 0, 0);
        }
    }
    {
        float wx0 = Wx2[c0], wx1 = Wx2[c1];
        float bb0 = bx1[c0], bb1 = bx1[c1];
        float gp[8][4];
#pragma unroll
        for (int rt = 0; rt < 8; ++rt)
#pragma unroll
            for (int r = 0; r < 4; ++r)
                gp[rt][r] = silu_f(acc[rt][0][r] + bb0) * wx0 +
                            silu_f(acc[rt][1][r] + bb1) * wx1;
#pragma unroll
        for (int m = 1; m < 16; m <<= 1)
#pragma unroll
            for (int rt = 0; rt < 8; ++rt)
#pragma unroll
                for (int r = 0; r < 4; ++r)
                    gp[rt][r] += __shfl_xor(gp[rt][r], m, 64);
        if (lc == 0) {
#pragma unroll
            for (int rt = 0; rt < 8; ++rt)
#pragma unroll
                for (int r = 0; r < 4; ++r)
                    atomicAdd(&sGate[rt * 16 + quad * 4 + r], gp[rt][r]);
        }
    }
    __syncthreads();

    if (tid < 128) {
        float g = sGate[tid] + bx2[0];
        int d = s_dst[tid];
        atomicAdd(&dxb[(size_t)d * 3 + 0], s_dir[tid * 3 + 0] * g);
        atomicAdd(&dxb[(size_t)d * 3 + 1], s_dir[tid * 3 + 1] * g);
        atomicAdd(&dxb[(size_t)d * 3 + 2], s_dir[tid * 3 + 2] * g);
    }
}

__global__ __launch_bounds__(256, 3)
void egnn_node_mfma(const float* __restrict__ h, const float* __restrict__ x,
                    const float* __restrict__ agg, const float* __restrict__ dxb,
                    const short* __restrict__ pWh1, const short* __restrict__ pWh2,
                    const float* __restrict__ bh1, const float* __restrict__ bh2,
                    const float* __restrict__ ln_g, const float* __restrict__ ln_b,
                    float* __restrict__ hout, float* __restrict__ xout) {
    __shared__ __align__(16) short sA[128 * SA_STRIDE];
    __shared__ __align__(16) short sT[128 * 128];
    __shared__ float sS1[128], sS2[128];

    const int tid = threadIdx.x;
    const int lane = tid & 63;
    const int w = tid >> 6;
    const int lc = lane & 15;
    const int quad = lane >> 4;
    const int n0 = blockIdx.x * 128;
    const int srow = tid >> 1;
    const int hf = tid & 1;

    if (tid < 128) { sS1[tid] = 0.0f; sS2[tid] = 0.0f; }

    const int ct0 = 2 * w, ct1 = 2 * w + 1;
    const int c0 = ct0 * 16 + lc, c1 = c0 + 16;

    floatx4 acc[8][2];
#pragma unroll
    for (int rt = 0; rt < 8; ++rt)
#pragma unroll
        for (int ct = 0; ct < 2; ++ct)
#pragma unroll
            for (int r = 0; r < 4; ++r) acc[rt][ct][r] = 0.0f;

    // ---- phi_h layer 1: [h | agg] (K=256) ----
    for (int kc = 0; kc < 8; ++kc) {
        {
            int n = n0 + srow;
            if (n >= N_NODES) n = N_NODES - 1;
            int koff = (kc & 3) * 32 + hf * 16;
            const float4* p = (kc < 4) ? (const float4*)&h[(size_t)n * HDIM + koff]
                                       : (const float4*)&agg[(size_t)n * HDIM + koff];
            float tmp[16];
#pragma unroll
            for (int q = 0; q < 4; ++q) {
                float4 v = p[q];
                tmp[4 * q + 0] = v.x; tmp[4 * q + 1] = v.y;
                tmp[4 * q + 2] = v.z; tmp[4 * q + 3] = v.w;
            }
            unsigned wd[8];
#pragma unroll
            for (int i = 0; i < 8; ++i)
                wd[i] = f2bf_u(tmp[2 * i]) | (f2bf_u(tmp[2 * i + 1]) << 16);
            uint4* dst = (uint4*)&sA[srow * SA_STRIDE + hf * 16];
            dst[0] = make_uint4(wd[0], wd[1], wd[2], wd[3]);
            dst[1] = make_uint4(wd[4], wd[5], wd[6], wd[7]);
        }
        __syncthreads();
        bf16x8 b0 = *(const bf16x8*)&pWh1[((size_t)(kc * 8 + ct0) * 64 + lane) * 8];
        bf16x8 b1 = *(const bf16x8*)&pWh1[((size_t)(kc * 8 + ct1) * 64 + lane) * 8];
#pragma unroll
        for (int rt = 0; rt < 8; ++rt) {
            bf16x8 a = *(const bf16x8*)&sA[(rt * 16 + lc) * SA_STRIDE + quad * 8];
            acc[rt][0] = __builtin_amdgcn_mfma_f32_16x16x32_bf16(a, b0, acc[rt][0], 0, 0, 0);
            acc[rt][1] = __builtin_amdgcn_mfma_f32_16x16x32_bf16(a, b1, acc[rt][1], 0, 0, 0);
        }
        __syncthreads();
    }
    {
        float bb0 = bh1[c0], bb1 = bh1[c1];
#pragma unroll
        for (int rt = 0; rt < 8; ++rt)
#pragma unroll
            for (int r = 0; r < 4; ++r) {
                int row = rt * 16 + quad * 4 + r;
                sT[sT_idx(row, c0)] = f2bf(silu_f(acc[rt][0][r] + bb0));
                sT[sT_idx(row, c1)] = f2bf(silu_f(acc[rt][1][r] + bb1));
            }
    }
    __syncthreads();

    // ---- phi_h layer 2 ----
#pragma unroll
    for (int rt = 0; rt < 8; ++rt)
#pragma unroll
        for (int ct = 0; ct < 2; ++ct)
#pragma unroll
            for (int r = 0; r < 4; ++r) acc[rt][ct][r] = 0.0f;

    for (int kc = 0; kc < 4; ++kc) {
        bf16x8 b0 = *(const bf16x8*)&pWh2[((size_t)(kc * 8 + ct0) * 64 + lane) * 8];
        bf16x8 b1 = *(const bf16x8*)&pWh2[((size_t)(kc * 8 + ct1) * 64 + lane) * 8];
#pragma unroll
        for (int rt = 0; rt < 8; ++rt) {
            int kb = (kc * 4 + quad) ^ ((lc >> 1) & 7);
            bf16x8 a = *(const bf16x8*)&sT[(rt * 16 + lc) * 128 + kb * 8];
            acc[rt][0] = __builtin_amdgcn_mfma_f32_16x16x32_bf16(a, b0, acc[rt][0], 0, 0, 0);
            acc[rt][1] = __builtin_amdgcn_mfma_f32_16x16x32_bf16(a, b1, acc[rt][1], 0, 0, 0);
        }
    }

    // ---- residual + LayerNorm ----
    {
        float bb0 = bh2[c0], bb1 = bh2[c1];
#pragma unroll
        for (int rt = 0; rt < 8; ++rt)
#pragma unroll
            for (int r = 0; r < 4; ++r) {
                int row = rt * 16 + quad * 4 + r;
                int n = n0 + row;
                int nc = (n < N_NODES) ? n : (N_NODES - 1);
                float v0 = acc[rt][0][r] + bb0 + h[(size_t)nc * HDIM + c0];
                float v1 = acc[rt][1][r] + bb1 + h[(size_t)nc * HDIM + c1];
                acc[rt][0][r] = v0;
                acc[rt][1][r] = v1;
                float s1 = v0 + v1;
                float s2 = v0 * v0 + v1 * v1;
#pragma unroll
                for (int m = 1; m < 16; m <<= 1) {
                    s1 += __shfl_xor(s1, m, 64);
                    s2 += __shfl_xor(s2, m, 64);
                }
                if (lc == 0) {
                    atomicAdd(&sS1[row], s1);
                    atomicAdd(&sS2[row], s2);
                }
            }
    }
    __syncthreads();
    {
        float g0 = ln_g[c0], g1 = ln_g[c1];
        float lb0 = ln_b[c0], lb1 = ln_b[c1];
#pragma unroll
        for (int rt = 0; rt < 8; ++rt)
#pragma unroll
            for (int r = 0; r < 4; ++r) {
                int row = rt * 16 + quad * 4 + r;
                int n = n0 + row;
                if (n < N_NODES) {
                    float mu = sS1[row] * (1.0f / 128.0f);
                    float var = sS2[row] * (1.0f / 128.0f) - mu * mu;
                    float rs = rsqrtf(var + 1e-5f);
                    hout[(size_t)n * HDIM + c0] = (acc[rt][0][r] - mu) * rs * g0 + lb0;
                    hout[(size_t)n * HDIM + c1] = (acc[rt][1][r] - mu) * rs * g1 + lb1;
                }
            }
    }

    // ---- x_out = x + dx ----
    for (int f = tid; f < 384; f += 256) {
        int n = n0 + f / 3;
        int d = f - (f / 3) * 3;
        if (n < N_NODES) xout[(size_t)n * 3 + d] = x[(size_t)n * 3 + d] + dxb[(size_t)n * 3 + d];
    }
}

extern "C" void kernel_launch(void* const* d_in, const int* in_sizes, int n_in,
                              void* d_out, int out_size, void* d_ws, size_t ws_size,
                              hipStream_t stream) {
    (void)in_sizes; (void)n_in; (void)out_size;

    const float* h   = (const float*)d_in[0];
    const float* x   = (const float*)d_in[1];
    const int*   ei  = (const int*)d_in[2];
    const float* ea  = (const float*)d_in[3];
    const float* We1 = (const float*)d_in[4];
    const float* be1 = (const float*)d_in[5];
    const float* We2 = (const float*)d_in[6];
    const float* be2 = (const float*)d_in[7];
    const float* Wh1 = (const float*)d_in[8];
    const float* bh1 = (const float*)d_in[9];
    const float* Wh2 = (const float*)d_in[10];
    const float* bh2 = (const float*)d_in[11];
    const float* Wx1 = (const float*)d_in[12];
    const float* bx1 = (const float*)d_in[13];
    const float* Wx2 = (const float*)d_in[14];
    const float* bx2 = (const float*)d_in[15];
    const float* lng = (const float*)d_in[16];
    const float* lnb = (const float*)d_in[17];

    float* hout = (float*)d_out;
    float* xout = hout + (size_t)N_NODES * HDIM;

    // packed weight layout (bf16 elems): We1 9 chunks, We2 4, Wx1 4, Wh1 8, Wh2 4
    const size_t CH = 8 * 64 * 8;                     // 4096 elems per k-chunk
    const size_t oWe1 = 0, oWe2 = 9 * CH, oWx1 = 13 * CH, oWh1 = 17 * CH, oWh2 = 25 * CH;
    const size_t pwElems = 29 * CH;                   // 118784 bf16 = 237568 B

    const size_t aggElems = (size_t)N_NODES * HDIM;   // 6.4M floats
    const size_t dxbElems = (size_t)N_NODES * 3;
    const size_t aggB = aggElems * 4, dxbB = dxbElems * 4, pwB = pwElems * 2;

    float* agg; float* dxb; short* pw;
    char* ws = (char*)d_ws;
    if (ws_size >= aggB + dxbB + pwB) {
        agg = (float*)ws;
        dxb = (float*)(ws + aggB);
        pw  = (short*)(ws + aggB + dxbB);
    } else {
        // fallback: weights in ws, agg/dxb alias d_out (node kernel reads its
        // agg/dxb rows before overwriting them with hout/xout)
        pw  = (short*)ws;
        agg = (float*)d_out;
        dxb = agg + aggElems;
    }

    hipMemsetAsync(agg, 0, aggB, stream);
    hipMemsetAsync(dxb, 0, dxbB, stream);

    pack_w_kernel<<<(9 * 512 + 255) / 256, 256, 0, stream>>>(We1, pw + oWe1, 273, 9 * 512);
    pack_w_kernel<<<(4 * 512 + 255) / 256, 256, 0, stream>>>(We2, pw + oWe2, 128, 4 * 512);
    pack_w_kernel<<<(4 * 512 + 255) / 256, 256, 0, stream>>>(Wx1, pw + oWx1, 128, 4 * 512);
    pack_w_kernel<<<(8 * 512 + 255) / 256, 256, 0, stream>>>(Wh1, pw + oWh1, 256, 8 * 512);
    pack_w_kernel<<<(4 * 512 + 255) / 256, 256, 0, stream>>>(Wh2, pw + oWh2, 128, 4 * 512);

    egnn_edge_mfma<<<N_EDGES / 128, 256, 0, stream>>>(
        h, x, ei, ea, pw + oWe1, pw + oWe2, pw + oWx1,
        be1, be2, bx1, Wx2, bx2, agg, dxb);

    egnn_node_mfma<<<(N_NODES + 127) / 128, 256, 0, stream>>>(
        h, x, agg, dxb, pw + oWh1, pw + oWh2,
        bh1, bh2, lng, lnb, hout, xout);
}